// Round 2
// baseline (40863.315 us; speedup 1.0000x reference)
//
#include <hip/hip_runtime.h>
#include <math.h>

#define T_ 100
#define B_ 64
#define S_ 128
#define E_ 512
#define H_ 1024
#define C_ 512
#define V_ 32000
#define TS_ 99            // T-1 steps
#define R_ (TS_ * B_)     // 6336 rows
#define MP_ 6400          // rows padded to multiple of 128 for MFMA
#define NT2 250           // vocab n-tiles of 128
#define NB_ 256           // persistent-kernel grid

typedef unsigned short ushort_t;
typedef __attribute__((ext_vector_type(8))) short short8;
typedef __attribute__((ext_vector_type(4))) float f32x4;

__device__ __forceinline__ float sigm_(float x) { return 1.0f / (1.0f + __expf(-x)); }
__device__ __forceinline__ float tanh_(float x) { float e = __expf(2.0f * x); return 1.0f - 2.0f / (e + 1.0f); }
__device__ __forceinline__ ushort_t f2bf(float f) {
    unsigned u = __float_as_uint(f);
    unsigned r = (u + 0x7FFF + ((u >> 16) & 1)) >> 16;
    return (ushort_t)r;
}
__device__ __forceinline__ float bf2f(ushort_t u) { return __uint_as_float(((unsigned)u) << 16); }

__device__ __forceinline__ float wred(float v) {
    #pragma unroll
    for (int o = 32; o; o >>= 1) v += __shfl_down(v, o);
    return v;
}
__device__ __forceinline__ float wmax(float v) {
    #pragma unroll
    for (int o = 32; o; o >>= 1) v = fmaxf(v, __shfl_down(v, o));
    return v;
}

// device-scope grid barrier (all NB_ blocks co-resident by construction)
__device__ __forceinline__ void gbar(unsigned* cnt, unsigned target) {
    __syncthreads();
    if (threadIdx.x == 0) {
        __threadfence();   // release: make this block's stores visible device-wide
        __hip_atomic_fetch_add(cnt, 1u, __ATOMIC_ACQ_REL, __HIP_MEMORY_SCOPE_AGENT);
        while (__hip_atomic_load(cnt, __ATOMIC_ACQUIRE, __HIP_MEMORY_SCOPE_AGENT) < target)
            __builtin_amdgcn_s_sleep(2);
        __threadfence();   // acquire: invalidate stale cached lines
    }
    __syncthreads();
}

// 64x64 output tile, K=256 slice, bf16 MFMA (4 waves; wave w -> cols w*16..+15).
__device__ __forceinline__ void gemm64(const ushort_t* __restrict__ Ap, int lda,
                                       const ushort_t* __restrict__ Wp,
                                       float* __restrict__ Pout, int ldP,
                                       ushort_t* As, ushort_t* Bs) {
    const int tid = threadIdx.x;
    const int w = tid >> 6, lane = tid & 63;
    const int quad = lane >> 4, l16 = lane & 15;
    f32x4 acc[4] = {};
    #pragma unroll
    for (int kc = 0; kc < 256; kc += 64) {
        __syncthreads();
        #pragma unroll
        for (int i = 0; i < 2; ++i) {
            int cid = i * 256 + tid;
            int row = cid >> 3, c8 = cid & 7;
            *(uint4*)(&As[row * 72 + c8 * 8]) = *(const uint4*)(Ap + (size_t)row * lda + kc + c8 * 8);
            *(uint4*)(&Bs[row * 72 + c8 * 8]) = *(const uint4*)(Wp + (size_t)row * lda + kc + c8 * 8);
        }
        __syncthreads();
        #pragma unroll
        for (int ks2 = 0; ks2 < 2; ++ks2) {
            short8 bfrag = *(const short8*)(&Bs[(w * 16 + l16) * 72 + ks2 * 32 + quad * 8]);
            #pragma unroll
            for (int i = 0; i < 4; ++i) {
                short8 afrag = *(const short8*)(&As[(i * 16 + l16) * 72 + ks2 * 32 + quad * 8]);
                acc[i] = __builtin_amdgcn_mfma_f32_16x16x32_bf16(afrag, bfrag, acc[i], 0, 0, 0);
            }
        }
    }
    const int col = w * 16 + l16;
    #pragma unroll
    for (int i = 0; i < 4; ++i)
        #pragma unroll
        for (int r = 0; r < 4; ++r)
            Pout[(size_t)(i * 16 + quad * 4 + r) * ldP + col] = acc[i][r];
}

// ---------------------------------------------------------------------------
// Persistent decode loop: the whole 99-step recurrence in one kernel.
// Phases per step: gh0 | gate0 | gh1+hid | attn | gi1 | gate1, grid-barriered.
// ---------------------------------------------------------------------------
__global__ __launch_bounds__(256) void decode_loop(
    const ushort_t* __restrict__ gi0_bf,
    const ushort_t* __restrict__ Whh0,
    const float* __restrict__ bi0, const float* __restrict__ bh0,
    const ushort_t* __restrict__ Wih1, const ushort_t* __restrict__ Whh1,
    const float* __restrict__ bi1, const float* __restrict__ bh1,
    const ushort_t* __restrict__ Wh2c, const float* __restrict__ wmlp,
    const ushort_t* __restrict__ ctxp_bf, const ushort_t* __restrict__ ctx_bf,
    float* __restrict__ P, float* __restrict__ Ph,
    float* __restrict__ h1f, ushort_t* __restrict__ h1bf, ushort_t* __restrict__ zbf,
    float* __restrict__ h2f, ushort_t* __restrict__ h2bf,
    unsigned* __restrict__ cnt) {
    __shared__ __align__(16) ushort_t As[64 * 72];
    __shared__ __align__(16) ushort_t Bs[64 * 72];
    const int blk = blockIdx.x;
    const int tid = threadIdx.x;
    unsigned ep = 0;
    for (int t = 0; t < TS_; ++t) {
        const int cur = t & 1, prv = cur ^ 1;
        // ---- P1: gh0 = h2(t-1) @ Whh0^T -> P[0..3] (skip at t=0: h_prev=0)
        if (t && blk < 192) {
            int ct = blk % 48, ks = blk / 48;
            gemm64(h2bf + (size_t)(t - 1) * B_ * H_ + ks * 256, H_,
                   Whh0 + (size_t)(ct * 64) * H_ + ks * 256,
                   P + (size_t)ks * 64 * 3072 + ct * 64, 3072, As, Bs);
        }
        gbar(cnt, NB_ * ++ep);
        // ---- P2: gate0 -> h1
        {
            int p = blk * 256 + tid;
            int b = p >> 10, j = p & 1023;
            const ushort_t* g = gi0_bf + (size_t)(t * B_ + b) * 3072;
            float ir = bi0[j] + bf2f(g[j]);
            float iz = bi0[1024 + j] + bf2f(g[1024 + j]);
            float in_ = bi0[2048 + j] + bf2f(g[2048 + j]);
            float hr = bh0[j], hz = bh0[1024 + j], hn = bh0[2048 + j];
            float hprev = 0.0f;
            if (t) {
                #pragma unroll
                for (int ks = 0; ks < 4; ++ks) {
                    const float* q = P + ((size_t)ks * 64 + b) * 3072;
                    hr += q[j]; hz += q[1024 + j]; hn += q[2048 + j];
                }
                hprev = h2f[(size_t)prv * (B_ * H_) + b * 1024 + j];
            }
            float r = sigm_(ir + hr), z = sigm_(iz + hz);
            float n = tanh_(in_ + r * hn);
            float h = (1.0f - z) * n + z * hprev;
            h1f[b * 1024 + j] = h;
            h1bf[b * 1024 + j] = f2bf(h);
        }
        gbar(cnt, NB_ * ++ep);
        // ---- P3: gh1 = h1 @ Whh1^T -> P[0..3]; hid = h1 @ Wh2c^T -> Ph[0..3]
        if (blk < 192) {
            int ct = blk % 48, ks = blk / 48;
            gemm64(h1bf + ks * 256, H_, Whh1 + (size_t)(ct * 64) * H_ + ks * 256,
                   P + (size_t)ks * 64 * 3072 + ct * 64, 3072, As, Bs);
        } else if (blk < 224) {
            int q = blk - 192;
            int ct = q % 8, ks = q / 8;
            gemm64(h1bf + ks * 256, H_, Wh2c + (size_t)(ct * 64) * H_ + ks * 256,
                   Ph + (size_t)ks * 64 * 512 + ct * 64, 512, As, Bs);
        }
        gbar(cnt, NB_ * ++ep);
        // ---- P4: attention -> zbf   (one block per batch row)
        if (blk < 64) {
            float* hd = (float*)As;                 // 512 f32 (2048 B)
            float* wm = (float*)(As + 2048);        // next 2048 B (As is 9216 B)
            float* sc = (float*)Bs;                 // 512 B
            const int b = blk;
            for (int k = tid; k < 512; k += 256) {
                float s = 0;
                #pragma unroll
                for (int p2 = 0; p2 < 4; ++p2) s += Ph[((size_t)p2 * 64 + b) * 512 + k];
                hd[k] = s;
                wm[k] = wmlp[k];
            }
            __syncthreads();
            const int wave = tid >> 6, lane = tid & 63;
            for (int s = wave; s < 128; s += 4) {
                const ushort_t* cp = ctxp_bf + ((size_t)s * B_ + b) * 512 + lane * 8;
                short8 v = *(const short8*)cp;
                float acc = 0;
                #pragma unroll
                for (int k = 0; k < 8; ++k) {
                    int c = lane * 8 + k;
                    acc += tanh_(bf2f((ushort_t)v[k]) + hd[c]) * wm[c];
                }
                acc = wred(acc);
                if (lane == 0) sc[s] = acc;
            }
            __syncthreads();
            if (wave == 0) {
                float s0 = sc[lane], s1 = sc[lane + 64];
                float m = fmaxf(s0, s1);
                m = wmax(m); m = __shfl(m, 0);
                float e0 = __expf(s0 - m), e1 = __expf(s1 - m);
                float ssum = wred(e0 + e1); ssum = __shfl(ssum, 0);
                float inv = 1.0f / ssum;
                sc[lane] = e0 * inv; sc[lane + 64] = e1 * inv;
            }
            __syncthreads();
            {
                const int c = tid * 2;
                float a0 = 0, a1 = 0;
                #pragma unroll 8
                for (int s = 0; s < 128; ++s) {
                    ushort2 u = *(const ushort2*)(ctx_bf + ((size_t)s * B_ + b) * 512 + c);
                    float w_ = sc[s];
                    a0 = fmaf(w_, bf2f(u.x), a0);
                    a1 = fmaf(w_, bf2f(u.y), a1);
                }
                *(ushort2*)(zbf + (size_t)b * 512 + c) = make_ushort2(f2bf(a0), f2bf(a1));
            }
        }
        gbar(cnt, NB_ * ++ep);
        // ---- P5: gi1 = z @ Wih1^T -> P[4..5]
        if (blk < 96) {
            int ct = blk % 48, ks = blk / 48;   // ks in {0,1}
            gemm64(zbf + ks * 256, C_, Wih1 + (size_t)(ct * 64) * C_ + ks * 256,
                   P + (size_t)(4 + ks) * 64 * 3072 + ct * 64, 3072, As, Bs);
        }
        gbar(cnt, NB_ * ++ep);
        // ---- P6: gate1 -> h2 (fp32 ping-pong + bf16 history)
        {
            int p = blk * 256 + tid;
            int b = p >> 10, j = p & 1023;
            float ir = bi1[j], iz = bi1[1024 + j], in_ = bi1[2048 + j];
            float hr = bh1[j], hz = bh1[1024 + j], hn = bh1[2048 + j];
            #pragma unroll
            for (int ks = 4; ks < 6; ++ks) {
                const float* q = P + ((size_t)ks * 64 + b) * 3072;
                ir += q[j]; iz += q[1024 + j]; in_ += q[2048 + j];
            }
            #pragma unroll
            for (int ks = 0; ks < 4; ++ks) {
                const float* q = P + ((size_t)ks * 64 + b) * 3072;
                hr += q[j]; hz += q[1024 + j]; hn += q[2048 + j];
            }
            float hprev = h1f[b * 1024 + j];
            float r = sigm_(ir + hr), z = sigm_(iz + hz);
            float n = tanh_(in_ + r * hn);
            float h = (1.0f - z) * n + z * hprev;
            h2f[(size_t)cur * (B_ * H_) + b * 1024 + j] = h;
            h2bf[(size_t)t * (B_ * H_) + b * 1024 + j] = f2bf(h);
        }
        gbar(cnt, NB_ * ++ep);
    }
}

// ---------------------------------------------------------------------------
// bf16 MFMA GEMM-NT, 128x128 tile. EPI==0: fp32 store (+opt bias).
// EPI==1: tanh(acc+bias) -> fp32 + bf16. EPI==2: fused LSE partials.
// EPI==3: bf16-only store (no bias).
// ---------------------------------------------------------------------------
template <int EPI>
__global__ __launch_bounds__(256) void mfma_nt(const ushort_t* __restrict__ A,
                                               const ushort_t* __restrict__ Bw,
                                               const float* __restrict__ bias,
                                               float* __restrict__ Cf,
                                               ushort_t* __restrict__ Cbf,
                                               float2* __restrict__ pp,
                                               int N, int K, int NT) {
    __shared__ ushort_t As[128 * 72];
    __shared__ ushort_t Bs[128 * 72];
    __shared__ float smM[2][128], smS[2][128];
    const int tid = threadIdx.x;
    const int m0 = blockIdx.y * 128, n0 = blockIdx.x * 128;
    const int w = tid >> 6, lane = tid & 63;
    const int quad = lane >> 4, l16 = lane & 15;
    f32x4 acc[4][4] = {};
    for (int kc = 0; kc < K; kc += 64) {
        __syncthreads();
        #pragma unroll
        for (int i = 0; i < 4; ++i) {
            int cid = i * 256 + tid;
            int row = cid >> 3, c8 = cid & 7;
            uint4 va = *(const uint4*)(A + (size_t)(m0 + row) * K + kc + c8 * 8);
            *(uint4*)(&As[row * 72 + c8 * 8]) = va;
            uint4 vb = *(const uint4*)(Bw + (size_t)(n0 + row) * K + kc + c8 * 8);
            *(uint4*)(&Bs[row * 72 + c8 * 8]) = vb;
        }
        __syncthreads();
        #pragma unroll
        for (int ks = 0; ks < 2; ++ks) {
            short8 af[4], bfr[4];
            #pragma unroll
            for (int i = 0; i < 4; ++i)
                af[i] = *(const short8*)(&As[((w >> 1) * 64 + i * 16 + l16) * 72 + ks * 32 + quad * 8]);
            #pragma unroll
            for (int j = 0; j < 4; ++j)
                bfr[j] = *(const short8*)(&Bs[((w & 1) * 64 + j * 16 + l16) * 72 + ks * 32 + quad * 8]);
            #pragma unroll
            for (int i = 0; i < 4; ++i)
                #pragma unroll
                for (int j = 0; j < 4; ++j)
                    acc[i][j] = __builtin_amdgcn_mfma_f32_16x16x32_bf16(af[i], bfr[j], acc[i][j], 0, 0, 0);
        }
    }
    const int colbase = n0 + (w & 1) * 64;
    const int rowbase = m0 + (w >> 1) * 64;
    if (EPI == 0) {
        #pragma unroll
        for (int j = 0; j < 4; ++j) {
            int col = colbase + j * 16 + l16;
            float bv = bias ? bias[col] : 0.0f;
            #pragma unroll
            for (int i = 0; i < 4; ++i)
                #pragma unroll
                for (int r = 0; r < 4; ++r) {
                    int row = rowbase + i * 16 + quad * 4 + r;
                    Cf[(size_t)row * N + col] = acc[i][j][r] + bv;
                }
        }
    } else if (EPI == 1) {
        #pragma unroll
        for (int j = 0; j < 4; ++j) {
            int col = colbase + j * 16 + l16;
            float bv = bias[col];
            #pragma unroll
            for (int i = 0; i < 4; ++i)
                #pragma unroll
                for (int r = 0; r < 4; ++r) {
                    int row = rowbase + i * 16 + quad * 4 + r;
                    float v = tanh_(acc[i][j][r] + bv);
                    Cf[(size_t)row * N + col] = v;
                    Cbf[(size_t)row * N + col] = f2bf(v);
                }
        }
    } else if (EPI == 3) {
        #pragma unroll
        for (int j = 0; j < 4; ++j) {
            int col = colbase + j * 16 + l16;
            #pragma unroll
            for (int i = 0; i < 4; ++i)
                #pragma unroll
                for (int r = 0; r < 4; ++r) {
                    int row = rowbase + i * 16 + quad * 4 + r;
                    Cbf[(size_t)row * N + col] = f2bf(acc[i][j][r]);
                }
        }
    } else {  // EPI == 2: LSE partials
        float bv[4];
        #pragma unroll
        for (int j = 0; j < 4; ++j) bv[j] = bias[colbase + j * 16 + l16];
        #pragma unroll
        for (int i = 0; i < 4; ++i) {
            #pragma unroll
            for (int r = 0; r < 4; ++r) {
                float x0 = acc[i][0][r] + bv[0], x1 = acc[i][1][r] + bv[1];
                float x2 = acc[i][2][r] + bv[2], x3 = acc[i][3][r] + bv[3];
                float mx = fmaxf(fmaxf(x0, x1), fmaxf(x2, x3));
                #pragma unroll
                for (int o = 1; o < 16; o <<= 1) mx = fmaxf(mx, __shfl_xor(mx, o));
                float s = __expf(x0 - mx) + __expf(x1 - mx) + __expf(x2 - mx) + __expf(x3 - mx);
                #pragma unroll
                for (int o = 1; o < 16; o <<= 1) s += __shfl_xor(s, o);
                if (l16 == 0) {
                    int rr = (w >> 1) * 64 + i * 16 + quad * 4 + r;
                    smM[w & 1][rr] = mx;
                    smS[w & 1][rr] = s;
                }
            }
        }
        __syncthreads();
        if (tid < 128) {
            float ma = smM[0][tid], mb = smM[1][tid];
            float M = fmaxf(ma, mb);
            float S = smS[0][tid] * __expf(ma - M) + smS[1][tid] * __expf(mb - M);
            pp[(size_t)(m0 + tid) * NT + blockIdx.x] = make_float2(M, S);
        }
    }
}

// fp32 -> bf16 convert with zero-pad beyond n_valid. block 256, 4 elems/thread.
__global__ __launch_bounds__(256) void conv_bf16(const float* __restrict__ src,
                                                 ushort_t* __restrict__ dst,
                                                 long long n_valid, long long n_total) {
    long long base = ((long long)blockIdx.x * 256 + threadIdx.x) * 4;
    if (base >= n_total) return;
    ushort_t o[4] = {0, 0, 0, 0};
    if (base < n_valid) {
        float4 v = *(const float4*)(src + base);
        o[0] = f2bf(v.x); o[1] = f2bf(v.y); o[2] = f2bf(v.z); o[3] = f2bf(v.w);
    }
    *(ushort2*)(dst + base) = make_ushort2(o[0], o[1]);
    *(ushort2*)(dst + base + 2) = make_ushort2(o[2], o[3]);
}

// gather embedding rows to bf16 with zero pad rows r >= R_.
__global__ __launch_bounds__(128) void gather_emb_bf(const float* __restrict__ emb,
                                                     const int* __restrict__ y,
                                                     ushort_t* __restrict__ xbf) {
    const int r = blockIdx.x;
    ushort_t* dst = xbf + (size_t)r * 512 + threadIdx.x * 4;
    if (r >= R_) {
        *(ushort2*)(dst) = make_ushort2(0, 0);
        *(ushort2*)(dst + 2) = make_ushort2(0, 0);
        return;
    }
    const int tok = y[r];
    const float* src = emb + (size_t)tok * 512;
    float4 v = *(const float4*)(src + threadIdx.x * 4);
    *(ushort2*)(dst) = make_ushort2(f2bf(v.x), f2bf(v.y));
    *(ushort2*)(dst + 2) = make_ushort2(f2bf(v.z), f2bf(v.w));
}

__global__ void zero_u32(unsigned* p) { p[0] = 0u; }

// combine LSE partials + target logit -> per-row loss. grid = R_, block 64.
__global__ __launch_bounds__(64) void row_loss_k(const float2* __restrict__ pp,
                                                 const float* __restrict__ logit_all,
                                                 const float* __restrict__ Wv,
                                                 const float* __restrict__ bv,
                                                 const int* __restrict__ y,
                                                 float* __restrict__ rl) {
    const int r = blockIdx.x;
    const int lane = threadIdx.x;
    const int t = r / B_, b = r % B_;
    const int tgt = y[(t + 1) * B_ + b];
    float m = -1e30f;
    for (int i = lane; i < NT2; i += 64) m = fmaxf(m, pp[(size_t)r * NT2 + i].x);
    m = wmax(m); m = __shfl(m, 0);
    float s = 0;
    for (int i = lane; i < NT2; i += 64) {
        float2 p = pp[(size_t)r * NT2 + i];
        s += p.y * __expf(p.x - m);
    }
    s = wred(s);
    float d = 0;
    for (int k = lane; k < E_; k += 64) d += logit_all[(size_t)r * E_ + k] * Wv[(size_t)tgt * E_ + k];
    d = wred(d);
    if (lane == 0) {
        float lse = m + logf(s);
        rl[r] = (tgt != 0) ? (lse - (d + bv[tgt])) : 0.0f;
    }
}

__global__ __launch_bounds__(256) void sum_k(const float* __restrict__ rl, float* __restrict__ out) {
    float s = 0;
    for (int i = threadIdx.x; i < R_; i += 256) s += rl[i];
    __shared__ float red[4];
    s = wred(s);
    if ((threadIdx.x & 63) == 0) red[threadIdx.x >> 6] = s;
    __syncthreads();
    if (threadIdx.x == 0) out[0] = red[0] + red[1] + red[2] + red[3];
}

extern "C" void kernel_launch(void* const* d_in, const int* in_sizes, int n_in,
                              void* d_out, int out_size, void* d_ws, size_t ws_size,
                              hipStream_t stream) {
    const int*   y     = (const int*)d_in[0];
    const float* ctx   = (const float*)d_in[1];
    const float* emb   = (const float*)d_in[2];
    const float* W_ih0 = (const float*)d_in[3];
    const float* W_hh0 = (const float*)d_in[4];
    const float* b_ih0 = (const float*)d_in[5];
    const float* b_hh0 = (const float*)d_in[6];
    const float* W_ih1 = (const float*)d_in[7];
    const float* W_hh1 = (const float*)d_in[8];
    const float* b_ih1 = (const float*)d_in[9];
    const float* b_hh1 = (const float*)d_in[10];
    const float* W_c2c = (const float*)d_in[11];
    const float* W_h2c = (const float*)d_in[12];
    const float* w_mlp = (const float*)d_in[13];
    const float* W_h2o = (const float*)d_in[14];
    const float* b_h2o = (const float*)d_in[15];
    const float* W_o2p = (const float*)d_in[16];
    const float* b_o2p = (const float*)d_in[17];
    float* out = (float*)d_out;

    float* ws = (float*)d_ws;
    ushort_t* ctxp_bf = (ushort_t*)ws; ws += (size_t)S_ * B_ * C_ / 2;   // 8.4 MB
    ushort_t* ctx_bf  = (ushort_t*)ws; ws += (size_t)S_ * B_ * C_ / 2;   // 8.4 MB
    ushort_t* xe_bf   = (ushort_t*)ws; ws += (size_t)MP_ * E_ / 2;       // 6.6 MB (zero-padded)
    float* P          = ws; ws += (size_t)6 * 64 * 3072;                 // 4.7 MB
    float* Ph         = ws; ws += (size_t)4 * 64 * 512;                  // 0.5 MB
    float* h1f        = ws; ws += (size_t)B_ * H_;
    ushort_t* h1bf    = (ushort_t*)ws; ws += (size_t)B_ * H_ / 2;
    ushort_t* zbf     = (ushort_t*)ws; ws += (size_t)B_ * C_ / 2;
    float* h2f        = ws; ws += (size_t)2 * B_ * H_;                   // ping-pong fp32
    ushort_t* h2_bf   = (ushort_t*)ws; ws += (size_t)MP_ * H_ / 2;       // 13.1 MB history
    ushort_t* Wih0_bf = (ushort_t*)ws; ws += (size_t)3 * H_ * E_ / 2;
    ushort_t* Whh0_bf = (ushort_t*)ws; ws += (size_t)3 * H_ * H_ / 2;
    ushort_t* Wih1_bf = (ushort_t*)ws; ws += (size_t)3 * H_ * C_ / 2;
    ushort_t* Whh1_bf = (ushort_t*)ws; ws += (size_t)3 * H_ * H_ / 2;
    ushort_t* Wh2c_bf = (ushort_t*)ws; ws += (size_t)C_ * H_ / 2;
    ushort_t* Wc2c_bf = (ushort_t*)ws; ws += (size_t)C_ * C_ / 2;
    ushort_t* Wh2o_bf = (ushort_t*)ws; ws += (size_t)E_ * H_ / 2;
    ushort_t* Wo2p_bf = (ushort_t*)ws; ws += (size_t)V_ * E_ / 2;        // 32.8 MB
    unsigned* barcnt  = (unsigned*)ws; ws += 16;
    // union region: precompute ctx_p | loop gi0_bf | tail logit/lg/pp/rl
    float* uni        = ws; ws += (size_t)MP_ * 3072 / 2;                // 39.3 MB
    float* ctx_p      = uni;                                             // S*B*C fp32 (precompute)
    ushort_t* gi0_bf  = (ushort_t*)uni;                                  // MP_*3072 bf16 (loop)
    float* logit_all  = uni;                                             // MP_*E fp32 (tail)
    ushort_t* lg_bf   = (ushort_t*)(uni + (size_t)MP_ * E_);             // MP_*E bf16 (tail)
    float2* pp        = (float2*)(uni + (size_t)MP_ * E_ + (size_t)MP_ * E_ / 2);
    float* rl         = uni + (size_t)MP_ * E_ + (size_t)MP_ * E_ / 2 + (size_t)MP_ * NT2 * 2;

    #define CONVGRID(n) dim3((unsigned)(((n) / 4 + 255) / 256))

    // ---- batched precompute ----
    conv_bf16<<<CONVGRID((long long)S_ * B_ * C_), 256, 0, stream>>>(ctx, ctx_bf, (long long)S_ * B_ * C_, (long long)S_ * B_ * C_);
    conv_bf16<<<CONVGRID((long long)C_ * C_), 256, 0, stream>>>(W_c2c, Wc2c_bf, (long long)C_ * C_, (long long)C_ * C_);
    conv_bf16<<<CONVGRID((long long)3 * H_ * E_), 256, 0, stream>>>(W_ih0, Wih0_bf, (long long)3 * H_ * E_, (long long)3 * H_ * E_);
    conv_bf16<<<CONVGRID((long long)3 * H_ * H_), 256, 0, stream>>>(W_hh0, Whh0_bf, (long long)3 * H_ * H_, (long long)3 * H_ * H_);
    conv_bf16<<<CONVGRID((long long)3 * H_ * C_), 256, 0, stream>>>(W_ih1, Wih1_bf, (long long)3 * H_ * C_, (long long)3 * H_ * C_);
    conv_bf16<<<CONVGRID((long long)3 * H_ * H_), 256, 0, stream>>>(W_hh1, Whh1_bf, (long long)3 * H_ * H_, (long long)3 * H_ * H_);
    conv_bf16<<<CONVGRID((long long)C_ * H_), 256, 0, stream>>>(W_h2c, Wh2c_bf, (long long)C_ * H_, (long long)C_ * H_);
    conv_bf16<<<CONVGRID((long long)E_ * H_), 256, 0, stream>>>(W_h2o, Wh2o_bf, (long long)E_ * H_, (long long)E_ * H_);
    conv_bf16<<<CONVGRID((long long)V_ * E_), 256, 0, stream>>>(W_o2p, Wo2p_bf, (long long)V_ * E_, (long long)V_ * E_);
    gather_emb_bf<<<MP_, 128, 0, stream>>>(emb, y, xe_bf);
    // ctx_p = ctx @ W_c2c^T -> fp32 (union), then bf16
    mfma_nt<0><<<dim3(C_ / 128, (S_ * B_) / 128), 256, 0, stream>>>(ctx_bf, Wc2c_bf, nullptr,
                                                                    ctx_p, nullptr, nullptr, C_, C_, 0);
    conv_bf16<<<CONVGRID((long long)S_ * B_ * C_), 256, 0, stream>>>(ctx_p, ctxp_bf, (long long)S_ * B_ * C_, (long long)S_ * B_ * C_);
    // gi0_all = x_emb @ W_ih0^T for all steps -> bf16 (overwrites ctx_p region)
    mfma_nt<3><<<dim3(3072 / 128, MP_ / 128), 256, 0, stream>>>(xe_bf, Wih0_bf, nullptr,
                                                                nullptr, gi0_bf, nullptr, 3072, E_, 0);
    // zero h2_bf pad rows (R_..MP_)
    conv_bf16<<<CONVGRID((long long)(MP_ - R_) * H_), 256, 0, stream>>>((const float*)d_ws, h2_bf + (size_t)R_ * H_,
                                                                        0LL, (long long)(MP_ - R_) * H_);
    zero_u32<<<1, 1, 0, stream>>>(barcnt);

    // ---- the whole decode loop in ONE persistent kernel ----
    decode_loop<<<NB_, 256, 0, stream>>>(gi0_bf, Whh0_bf, b_ih0, b_hh0,
                                         Wih1_bf, Whh1_bf, b_ih1, b_hh1,
                                         Wh2c_bf, w_mlp, ctxp_bf, ctx_bf,
                                         P, Ph, h1f, h1bf, zbf, h2f, h2_bf, barcnt);

    // ---- batched tail (bf16 MFMA) ----
    mfma_nt<1><<<dim3(E_ / 128, MP_ / 128), 256, 0, stream>>>(h2_bf, Wh2o_bf, b_h2o,
                                                              logit_all, lg_bf, nullptr, E_, H_, 0);
    mfma_nt<2><<<dim3(V_ / 128, MP_ / 128), 256, 0, stream>>>(lg_bf, Wo2p_bf, b_o2p,
                                                              nullptr, nullptr, pp, V_, E_, NT2);
    row_loss_k<<<R_, 64, 0, stream>>>(pp, logit_all, W_o2p, b_o2p, y, rl);
    sum_k<<<1, 256, 0, stream>>>(rl, out);
}

// Round 3
// 16359.227 us; speedup vs baseline: 2.4979x; 2.4979x over previous
//
#include <hip/hip_runtime.h>
#include <math.h>

#define T_ 100
#define B_ 64
#define S_ 128
#define E_ 512
#define H_ 1024
#define C_ 512
#define V_ 32000
#define TS_ 99            // T-1 steps
#define R_ (TS_ * B_)     // 6336 rows
#define MP_ 6400          // rows padded to multiple of 128 for MFMA
#define NT2 250           // vocab n-tiles of 128
#define NB_ 256           // persistent-kernel grid

typedef unsigned short ushort_t;
typedef __attribute__((ext_vector_type(8))) short short8;
typedef __attribute__((ext_vector_type(4))) float f32x4;

__device__ __forceinline__ float sigm_(float x) { return 1.0f / (1.0f + __expf(-x)); }
__device__ __forceinline__ float tanh_(float x) { float e = __expf(2.0f * x); return 1.0f - 2.0f / (e + 1.0f); }
__device__ __forceinline__ ushort_t f2bf(float f) {
    unsigned u = __float_as_uint(f);
    unsigned r = (u + 0x7FFF + ((u >> 16) & 1)) >> 16;
    return (ushort_t)r;
}
__device__ __forceinline__ float bf2f(ushort_t u) { return __uint_as_float(((unsigned)u) << 16); }

__device__ __forceinline__ float wred(float v) {
    #pragma unroll
    for (int o = 32; o; o >>= 1) v += __shfl_down(v, o);
    return v;
}
__device__ __forceinline__ float wmax(float v) {
    #pragma unroll
    for (int o = 32; o; o >>= 1) v = fmaxf(v, __shfl_down(v, o));
    return v;
}

// ---------------------------------------------------------------------------
// Hierarchical grid barrier, RELAXED polling (no per-poll cache invalidates).
// bar layout (unsigned, 128B-strided lines):
//   grpCnt[g] @ g*32 (g=0..7) | glbCnt @ 256 | glbRel @ 288 | grpRel[g] @ (10+g)*32
// One release fence before arrive, one acquire fence after release observed.
// ---------------------------------------------------------------------------
__device__ __forceinline__ unsigned ld_rlx(unsigned* p) {
    return __hip_atomic_load(p, __ATOMIC_RELAXED, __HIP_MEMORY_SCOPE_AGENT);
}
__device__ __forceinline__ void st_rlx(unsigned* p, unsigned v) {
    __hip_atomic_store(p, v, __ATOMIC_RELAXED, __HIP_MEMORY_SCOPE_AGENT);
}

__device__ __forceinline__ void gbar(unsigned* bar, unsigned ep) {
    const int blk = blockIdx.x;
    const int g = blk >> 5;           // 8 groups of 32 blocks
    __syncthreads();
    if (threadIdx.x == 0) {
        __threadfence();              // release: writeback this block's stores
        __hip_atomic_fetch_add(&bar[g * 32], 1u, __ATOMIC_RELAXED, __HIP_MEMORY_SCOPE_AGENT);
        if ((blk & 31) == 0) {
            // group leader: wait for own group, then arrive globally
            while (ld_rlx(&bar[g * 32]) < 32u * ep) __builtin_amdgcn_s_sleep(4);
            __hip_atomic_fetch_add(&bar[256], 1u, __ATOMIC_RELAXED, __HIP_MEMORY_SCOPE_AGENT);
            if (blk == 0) {
                while (ld_rlx(&bar[256]) < 8u * ep) __builtin_amdgcn_s_sleep(4);
                st_rlx(&bar[288], ep);            // global release
            }
            while (ld_rlx(&bar[288]) < ep) __builtin_amdgcn_s_sleep(4);
            st_rlx(&bar[(10 + g) * 32], ep);      // group release
        }
        while (ld_rlx(&bar[(10 + g) * 32]) < ep) __builtin_amdgcn_s_sleep(4);
        __threadfence();              // acquire: invalidate stale lines (once)
    }
    __syncthreads();
}

// 64x64 output tile, K=256 slice, bf16 MFMA (4 waves; wave w -> cols w*16..+15).
__device__ __forceinline__ void gemm64(const ushort_t* __restrict__ Ap, int lda,
                                       const ushort_t* __restrict__ Wp,
                                       float* __restrict__ Pout, int ldP,
                                       ushort_t* As, ushort_t* Bs) {
    const int tid = threadIdx.x;
    const int w = tid >> 6, lane = tid & 63;
    const int quad = lane >> 4, l16 = lane & 15;
    f32x4 acc[4] = {};
    #pragma unroll
    for (int kc = 0; kc < 256; kc += 64) {
        __syncthreads();
        #pragma unroll
        for (int i = 0; i < 2; ++i) {
            int cid = i * 256 + tid;
            int row = cid >> 3, c8 = cid & 7;
            *(uint4*)(&As[row * 72 + c8 * 8]) = *(const uint4*)(Ap + (size_t)row * lda + kc + c8 * 8);
            *(uint4*)(&Bs[row * 72 + c8 * 8]) = *(const uint4*)(Wp + (size_t)row * lda + kc + c8 * 8);
        }
        __syncthreads();
        #pragma unroll
        for (int ks2 = 0; ks2 < 2; ++ks2) {
            short8 bfrag = *(const short8*)(&Bs[(w * 16 + l16) * 72 + ks2 * 32 + quad * 8]);
            #pragma unroll
            for (int i = 0; i < 4; ++i) {
                short8 afrag = *(const short8*)(&As[(i * 16 + l16) * 72 + ks2 * 32 + quad * 8]);
                acc[i] = __builtin_amdgcn_mfma_f32_16x16x32_bf16(afrag, bfrag, acc[i], 0, 0, 0);
            }
        }
    }
    const int col = w * 16 + l16;
    #pragma unroll
    for (int i = 0; i < 4; ++i)
        #pragma unroll
        for (int r = 0; r < 4; ++r)
            Pout[(size_t)(i * 16 + quad * 4 + r) * ldP + col] = acc[i][r];
}

// ---------------------------------------------------------------------------
// Persistent decode loop: the whole 99-step recurrence in one kernel.
// Phases per step: gh0 | gate0 | gh1+hid | attn | gi1 | gate1, grid-barriered.
// ---------------------------------------------------------------------------
__global__ __launch_bounds__(256) void decode_loop(
    const ushort_t* __restrict__ gi0_bf,
    const ushort_t* __restrict__ Whh0,
    const float* __restrict__ bi0, const float* __restrict__ bh0,
    const ushort_t* __restrict__ Wih1, const ushort_t* __restrict__ Whh1,
    const float* __restrict__ bi1, const float* __restrict__ bh1,
    const ushort_t* __restrict__ Wh2c, const float* __restrict__ wmlp,
    const ushort_t* __restrict__ ctxp_bf, const ushort_t* __restrict__ ctx_bf,
    float* __restrict__ P, float* __restrict__ Ph,
    float* __restrict__ h1f, ushort_t* __restrict__ h1bf, ushort_t* __restrict__ zbf,
    float* __restrict__ h2f, ushort_t* __restrict__ h2bf,
    unsigned* __restrict__ bar) {
    __shared__ __align__(16) ushort_t As[64 * 72];
    __shared__ __align__(16) ushort_t Bs[64 * 72];
    const int blk = blockIdx.x;
    const int tid = threadIdx.x;
    unsigned ep = 0;
    for (int t = 0; t < TS_; ++t) {
        const int cur = t & 1, prv = cur ^ 1;
        // ---- P1: gh0 = h2(t-1) @ Whh0^T -> P[0..3] (skip at t=0: h_prev=0)
        if (t && blk < 192) {
            int ct = blk % 48, ks = blk / 48;
            gemm64(h2bf + (size_t)(t - 1) * B_ * H_ + ks * 256, H_,
                   Whh0 + (size_t)(ct * 64) * H_ + ks * 256,
                   P + (size_t)ks * 64 * 3072 + ct * 64, 3072, As, Bs);
        }
        gbar(bar, ++ep);
        // ---- P2: gate0 -> h1
        {
            int p = blk * 256 + tid;
            int b = p >> 10, j = p & 1023;
            const ushort_t* g = gi0_bf + (size_t)(t * B_ + b) * 3072;
            float ir = bi0[j] + bf2f(g[j]);
            float iz = bi0[1024 + j] + bf2f(g[1024 + j]);
            float in_ = bi0[2048 + j] + bf2f(g[2048 + j]);
            float hr = bh0[j], hz = bh0[1024 + j], hn = bh0[2048 + j];
            float hprev = 0.0f;
            if (t) {
                #pragma unroll
                for (int ks = 0; ks < 4; ++ks) {
                    const float* q = P + ((size_t)ks * 64 + b) * 3072;
                    hr += q[j]; hz += q[1024 + j]; hn += q[2048 + j];
                }
                hprev = h2f[(size_t)prv * (B_ * H_) + b * 1024 + j];
            }
            float r = sigm_(ir + hr), z = sigm_(iz + hz);
            float n = tanh_(in_ + r * hn);
            float h = (1.0f - z) * n + z * hprev;
            h1f[b * 1024 + j] = h;
            h1bf[b * 1024 + j] = f2bf(h);
        }
        gbar(bar, ++ep);
        // ---- P3: gh1 = h1 @ Whh1^T -> P[0..3]; hid = h1 @ Wh2c^T -> Ph[0..3]
        if (blk < 192) {
            int ct = blk % 48, ks = blk / 48;
            gemm64(h1bf + ks * 256, H_, Whh1 + (size_t)(ct * 64) * H_ + ks * 256,
                   P + (size_t)ks * 64 * 3072 + ct * 64, 3072, As, Bs);
        } else if (blk < 224) {
            int q = blk - 192;
            int ct = q % 8, ks = q / 8;
            gemm64(h1bf + ks * 256, H_, Wh2c + (size_t)(ct * 64) * H_ + ks * 256,
                   Ph + (size_t)ks * 64 * 512 + ct * 64, 512, As, Bs);
        }
        gbar(bar, ++ep);
        // ---- P4: attention -> zbf   (one block per batch row)
        if (blk < 64) {
            float* hd = (float*)As;                 // 512 f32 (2048 B)
            float* wm = (float*)(As + 2048);        // next 2048 B (As is 9216 B)
            float* sc = (float*)Bs;                 // 512 B
            const int b = blk;
            for (int k = tid; k < 512; k += 256) {
                float s = 0;
                #pragma unroll
                for (int p2 = 0; p2 < 4; ++p2) s += Ph[((size_t)p2 * 64 + b) * 512 + k];
                hd[k] = s;
                wm[k] = wmlp[k];
            }
            __syncthreads();
            const int wave = tid >> 6, lane = tid & 63;
            for (int s = wave; s < 128; s += 4) {
                const ushort_t* cp = ctxp_bf + ((size_t)s * B_ + b) * 512 + lane * 8;
                short8 v = *(const short8*)cp;
                float acc = 0;
                #pragma unroll
                for (int k = 0; k < 8; ++k) {
                    int c = lane * 8 + k;
                    acc += tanh_(bf2f((ushort_t)v[k]) + hd[c]) * wm[c];
                }
                acc = wred(acc);
                if (lane == 0) sc[s] = acc;
            }
            __syncthreads();
            if (wave == 0) {
                float s0 = sc[lane], s1 = sc[lane + 64];
                float m = fmaxf(s0, s1);
                m = wmax(m); m = __shfl(m, 0);
                float e0 = __expf(s0 - m), e1 = __expf(s1 - m);
                float ssum = wred(e0 + e1); ssum = __shfl(ssum, 0);
                float inv = 1.0f / ssum;
                sc[lane] = e0 * inv; sc[lane + 64] = e1 * inv;
            }
            __syncthreads();
            {
                const int c = tid * 2;
                float a0 = 0, a1 = 0;
                #pragma unroll 8
                for (int s = 0; s < 128; ++s) {
                    ushort2 u = *(const ushort2*)(ctx_bf + ((size_t)s * B_ + b) * 512 + c);
                    float w_ = sc[s];
                    a0 = fmaf(w_, bf2f(u.x), a0);
                    a1 = fmaf(w_, bf2f(u.y), a1);
                }
                *(ushort2*)(zbf + (size_t)b * 512 + c) = make_ushort2(f2bf(a0), f2bf(a1));
            }
        }
        gbar(bar, ++ep);
        // ---- P5: gi1 = z @ Wih1^T -> P[4..5]
        if (blk < 96) {
            int ct = blk % 48, ks = blk / 48;   // ks in {0,1}
            gemm64(zbf + ks * 256, C_, Wih1 + (size_t)(ct * 64) * C_ + ks * 256,
                   P + (size_t)(4 + ks) * 64 * 3072 + ct * 64, 3072, As, Bs);
        }
        gbar(bar, ++ep);
        // ---- P6: gate1 -> h2 (fp32 ping-pong + bf16 history)
        {
            int p = blk * 256 + tid;
            int b = p >> 10, j = p & 1023;
            float ir = bi1[j], iz = bi1[1024 + j], in_ = bi1[2048 + j];
            float hr = bh1[j], hz = bh1[1024 + j], hn = bh1[2048 + j];
            #pragma unroll
            for (int ks = 4; ks < 6; ++ks) {
                const float* q = P + ((size_t)ks * 64 + b) * 3072;
                ir += q[j]; iz += q[1024 + j]; in_ += q[2048 + j];
            }
            #pragma unroll
            for (int ks = 0; ks < 4; ++ks) {
                const float* q = P + ((size_t)ks * 64 + b) * 3072;
                hr += q[j]; hz += q[1024 + j]; hn += q[2048 + j];
            }
            float hprev = h1f[b * 1024 + j];
            float r = sigm_(ir + hr), z = sigm_(iz + hz);
            float n = tanh_(in_ + r * hn);
            float h = (1.0f - z) * n + z * hprev;
            h2f[(size_t)cur * (B_ * H_) + b * 1024 + j] = h;
            h2bf[(size_t)t * (B_ * H_) + b * 1024 + j] = f2bf(h);
        }
        gbar(bar, ++ep);
    }
}

// ---------------------------------------------------------------------------
// bf16 MFMA GEMM-NT, 128x128 tile. EPI==0: fp32 store (+opt bias).
// EPI==1: tanh(acc+bias) -> fp32 + bf16. EPI==2: fused LSE partials.
// EPI==3: bf16-only store (no bias).
// ---------------------------------------------------------------------------
template <int EPI>
__global__ __launch_bounds__(256) void mfma_nt(const ushort_t* __restrict__ A,
                                               const ushort_t* __restrict__ Bw,
                                               const float* __restrict__ bias,
                                               float* __restrict__ Cf,
                                               ushort_t* __restrict__ Cbf,
                                               float2* __restrict__ pp,
                                               int N, int K, int NT) {
    __shared__ ushort_t As[128 * 72];
    __shared__ ushort_t Bs[128 * 72];
    __shared__ float smM[2][128], smS[2][128];
    const int tid = threadIdx.x;
    const int m0 = blockIdx.y * 128, n0 = blockIdx.x * 128;
    const int w = tid >> 6, lane = tid & 63;
    const int quad = lane >> 4, l16 = lane & 15;
    f32x4 acc[4][4] = {};
    for (int kc = 0; kc < K; kc += 64) {
        __syncthreads();
        #pragma unroll
        for (int i = 0; i < 4; ++i) {
            int cid = i * 256 + tid;
            int row = cid >> 3, c8 = cid & 7;
            uint4 va = *(const uint4*)(A + (size_t)(m0 + row) * K + kc + c8 * 8);
            *(uint4*)(&As[row * 72 + c8 * 8]) = va;
            uint4 vb = *(const uint4*)(Bw + (size_t)(n0 + row) * K + kc + c8 * 8);
            *(uint4*)(&Bs[row * 72 + c8 * 8]) = vb;
        }
        __syncthreads();
        #pragma unroll
        for (int ks = 0; ks < 2; ++ks) {
            short8 af[4], bfr[4];
            #pragma unroll
            for (int i = 0; i < 4; ++i)
                af[i] = *(const short8*)(&As[((w >> 1) * 64 + i * 16 + l16) * 72 + ks * 32 + quad * 8]);
            #pragma unroll
            for (int j = 0; j < 4; ++j)
                bfr[j] = *(const short8*)(&Bs[((w & 1) * 64 + j * 16 + l16) * 72 + ks * 32 + quad * 8]);
            #pragma unroll
            for (int i = 0; i < 4; ++i)
                #pragma unroll
                for (int j = 0; j < 4; ++j)
                    acc[i][j] = __builtin_amdgcn_mfma_f32_16x16x32_bf16(af[i], bfr[j], acc[i][j], 0, 0, 0);
        }
    }
    const int colbase = n0 + (w & 1) * 64;
    const int rowbase = m0 + (w >> 1) * 64;
    if (EPI == 0) {
        #pragma unroll
        for (int j = 0; j < 4; ++j) {
            int col = colbase + j * 16 + l16;
            float bv = bias ? bias[col] : 0.0f;
            #pragma unroll
            for (int i = 0; i < 4; ++i)
                #pragma unroll
                for (int r = 0; r < 4; ++r) {
                    int row = rowbase + i * 16 + quad * 4 + r;
                    Cf[(size_t)row * N + col] = acc[i][j][r] + bv;
                }
        }
    } else if (EPI == 1) {
        #pragma unroll
        for (int j = 0; j < 4; ++j) {
            int col = colbase + j * 16 + l16;
            float bv = bias[col];
            #pragma unroll
            for (int i = 0; i < 4; ++i)
                #pragma unroll
                for (int r = 0; r < 4; ++r) {
                    int row = rowbase + i * 16 + quad * 4 + r;
                    float v = tanh_(acc[i][j][r] + bv);
                    Cf[(size_t)row * N + col] = v;
                    Cbf[(size_t)row * N + col] = f2bf(v);
                }
        }
    } else if (EPI == 3) {
        #pragma unroll
        for (int j = 0; j < 4; ++j) {
            int col = colbase + j * 16 + l16;
            #pragma unroll
            for (int i = 0; i < 4; ++i)
                #pragma unroll
                for (int r = 0; r < 4; ++r) {
                    int row = rowbase + i * 16 + quad * 4 + r;
                    Cbf[(size_t)row * N + col] = f2bf(acc[i][j][r]);
                }
        }
    } else {  // EPI == 2: LSE partials
        float bv[4];
        #pragma unroll
        for (int j = 0; j < 4; ++j) bv[j] = bias[colbase + j * 16 + l16];
        #pragma unroll
        for (int i = 0; i < 4; ++i) {
            #pragma unroll
            for (int r = 0; r < 4; ++r) {
                float x0 = acc[i][0][r] + bv[0], x1 = acc[i][1][r] + bv[1];
                float x2 = acc[i][2][r] + bv[2], x3 = acc[i][3][r] + bv[3];
                float mx = fmaxf(fmaxf(x0, x1), fmaxf(x2, x3));
                #pragma unroll
                for (int o = 1; o < 16; o <<= 1) mx = fmaxf(mx, __shfl_xor(mx, o));
                float s = __expf(x0 - mx) + __expf(x1 - mx) + __expf(x2 - mx) + __expf(x3 - mx);
                #pragma unroll
                for (int o = 1; o < 16; o <<= 1) s += __shfl_xor(s, o);
                if (l16 == 0) {
                    int rr = (w >> 1) * 64 + i * 16 + quad * 4 + r;
                    smM[w & 1][rr] = mx;
                    smS[w & 1][rr] = s;
                }
            }
        }
        __syncthreads();
        if (tid < 128) {
            float ma = smM[0][tid], mb = smM[1][tid];
            float M = fmaxf(ma, mb);
            float S = smS[0][tid] * __expf(ma - M) + smS[1][tid] * __expf(mb - M);
            pp[(size_t)(m0 + tid) * NT + blockIdx.x] = make_float2(M, S);
        }
    }
}

// fp32 -> bf16 convert with zero-pad beyond n_valid. block 256, 4 elems/thread.
__global__ __launch_bounds__(256) void conv_bf16(const float* __restrict__ src,
                                                 ushort_t* __restrict__ dst,
                                                 long long n_valid, long long n_total) {
    long long base = ((long long)blockIdx.x * 256 + threadIdx.x) * 4;
    if (base >= n_total) return;
    ushort_t o[4] = {0, 0, 0, 0};
    if (base < n_valid) {
        float4 v = *(const float4*)(src + base);
        o[0] = f2bf(v.x); o[1] = f2bf(v.y); o[2] = f2bf(v.z); o[3] = f2bf(v.w);
    }
    *(ushort2*)(dst + base) = make_ushort2(o[0], o[1]);
    *(ushort2*)(dst + base + 2) = make_ushort2(o[2], o[3]);
}

// gather embedding rows to bf16 with zero pad rows r >= R_.
__global__ __launch_bounds__(128) void gather_emb_bf(const float* __restrict__ emb,
                                                     const int* __restrict__ y,
                                                     ushort_t* __restrict__ xbf) {
    const int r = blockIdx.x;
    ushort_t* dst = xbf + (size_t)r * 512 + threadIdx.x * 4;
    if (r >= R_) {
        *(ushort2*)(dst) = make_ushort2(0, 0);
        *(ushort2*)(dst + 2) = make_ushort2(0, 0);
        return;
    }
    const int tok = y[r];
    const float* src = emb + (size_t)tok * 512;
    float4 v = *(const float4*)(src + threadIdx.x * 4);
    *(ushort2*)(dst) = make_ushort2(f2bf(v.x), f2bf(v.y));
    *(ushort2*)(dst + 2) = make_ushort2(f2bf(v.z), f2bf(v.w));
}

__global__ __launch_bounds__(256) void zero_bar(unsigned* p) {
    for (int i = threadIdx.x; i < 1024; i += 256) p[i] = 0u;
}

// combine LSE partials + target logit -> per-row loss. grid = R_, block 64.
__global__ __launch_bounds__(64) void row_loss_k(const float2* __restrict__ pp,
                                                 const float* __restrict__ logit_all,
                                                 const float* __restrict__ Wv,
                                                 const float* __restrict__ bv,
                                                 const int* __restrict__ y,
                                                 float* __restrict__ rl) {
    const int r = blockIdx.x;
    const int lane = threadIdx.x;
    const int t = r / B_, b = r % B_;
    const int tgt = y[(t + 1) * B_ + b];
    float m = -1e30f;
    for (int i = lane; i < NT2; i += 64) m = fmaxf(m, pp[(size_t)r * NT2 + i].x);
    m = wmax(m); m = __shfl(m, 0);
    float s = 0;
    for (int i = lane; i < NT2; i += 64) {
        float2 p = pp[(size_t)r * NT2 + i];
        s += p.y * __expf(p.x - m);
    }
    s = wred(s);
    float d = 0;
    for (int k = lane; k < E_; k += 64) d += logit_all[(size_t)r * E_ + k] * Wv[(size_t)tgt * E_ + k];
    d = wred(d);
    if (lane == 0) {
        float lse = m + logf(s);
        rl[r] = (tgt != 0) ? (lse - (d + bv[tgt])) : 0.0f;
    }
}

__global__ __launch_bounds__(256) void sum_k(const float* __restrict__ rl, float* __restrict__ out) {
    float s = 0;
    for (int i = threadIdx.x; i < R_; i += 256) s += rl[i];
    __shared__ float red[4];
    s = wred(s);
    if ((threadIdx.x & 63) == 0) red[threadIdx.x >> 6] = s;
    __syncthreads();
    if (threadIdx.x == 0) out[0] = red[0] + red[1] + red[2] + red[3];
}

extern "C" void kernel_launch(void* const* d_in, const int* in_sizes, int n_in,
                              void* d_out, int out_size, void* d_ws, size_t ws_size,
                              hipStream_t stream) {
    const int*   y     = (const int*)d_in[0];
    const float* ctx   = (const float*)d_in[1];
    const float* emb   = (const float*)d_in[2];
    const float* W_ih0 = (const float*)d_in[3];
    const float* W_hh0 = (const float*)d_in[4];
    const float* b_ih0 = (const float*)d_in[5];
    const float* b_hh0 = (const float*)d_in[6];
    const float* W_ih1 = (const float*)d_in[7];
    const float* W_hh1 = (const float*)d_in[8];
    const float* b_ih1 = (const float*)d_in[9];
    const float* b_hh1 = (const float*)d_in[10];
    const float* W_c2c = (const float*)d_in[11];
    const float* W_h2c = (const float*)d_in[12];
    const float* w_mlp = (const float*)d_in[13];
    const float* W_h2o = (const float*)d_in[14];
    const float* b_h2o = (const float*)d_in[15];
    const float* W_o2p = (const float*)d_in[16];
    const float* b_o2p = (const float*)d_in[17];
    float* out = (float*)d_out;

    float* ws = (float*)d_ws;
    ushort_t* ctxp_bf = (ushort_t*)ws; ws += (size_t)S_ * B_ * C_ / 2;   // 8.4 MB
    ushort_t* ctx_bf  = (ushort_t*)ws; ws += (size_t)S_ * B_ * C_ / 2;   // 8.4 MB
    ushort_t* xe_bf   = (ushort_t*)ws; ws += (size_t)MP_ * E_ / 2;       // 6.6 MB (zero-padded)
    float* P          = ws; ws += (size_t)6 * 64 * 3072;                 // 4.7 MB
    float* Ph         = ws; ws += (size_t)4 * 64 * 512;                  // 0.5 MB
    float* h1f        = ws; ws += (size_t)B_ * H_;
    ushort_t* h1bf    = (ushort_t*)ws; ws += (size_t)B_ * H_ / 2;
    ushort_t* zbf     = (ushort_t*)ws; ws += (size_t)B_ * C_ / 2;
    float* h2f        = ws; ws += (size_t)2 * B_ * H_;                   // ping-pong fp32
    ushort_t* h2_bf   = (ushort_t*)ws; ws += (size_t)MP_ * H_ / 2;       // 13.1 MB history
    ushort_t* Wih0_bf = (ushort_t*)ws; ws += (size_t)3 * H_ * E_ / 2;
    ushort_t* Whh0_bf = (ushort_t*)ws; ws += (size_t)3 * H_ * H_ / 2;
    ushort_t* Wih1_bf = (ushort_t*)ws; ws += (size_t)3 * H_ * C_ / 2;
    ushort_t* Whh1_bf = (ushort_t*)ws; ws += (size_t)3 * H_ * H_ / 2;
    ushort_t* Wh2c_bf = (ushort_t*)ws; ws += (size_t)C_ * H_ / 2;
    ushort_t* Wc2c_bf = (ushort_t*)ws; ws += (size_t)C_ * C_ / 2;
    ushort_t* Wh2o_bf = (ushort_t*)ws; ws += (size_t)E_ * H_ / 2;
    ushort_t* Wo2p_bf = (ushort_t*)ws; ws += (size_t)V_ * E_ / 2;        // 32.8 MB
    unsigned* barcnt  = (unsigned*)ws; ws += 1024;
    // union region: precompute ctx_p | loop gi0_bf | tail logit/lg/pp/rl
    float* uni        = ws; ws += (size_t)MP_ * 3072 / 2;                // 39.3 MB
    float* ctx_p      = uni;                                             // S*B*C fp32 (precompute)
    ushort_t* gi0_bf  = (ushort_t*)uni;                                  // MP_*3072 bf16 (loop)
    float* logit_all  = uni;                                             // MP_*E fp32 (tail)
    ushort_t* lg_bf   = (ushort_t*)(uni + (size_t)MP_ * E_);             // MP_*E bf16 (tail)
    float2* pp        = (float2*)(uni + (size_t)MP_ * E_ + (size_t)MP_ * E_ / 2);
    float* rl         = uni + (size_t)MP_ * E_ + (size_t)MP_ * E_ / 2 + (size_t)MP_ * NT2 * 2;

    #define CONVGRID(n) dim3((unsigned)(((n) / 4 + 255) / 256))

    // ---- batched precompute ----
    conv_bf16<<<CONVGRID((long long)S_ * B_ * C_), 256, 0, stream>>>(ctx, ctx_bf, (long long)S_ * B_ * C_, (long long)S_ * B_ * C_);
    conv_bf16<<<CONVGRID((long long)C_ * C_), 256, 0, stream>>>(W_c2c, Wc2c_bf, (long long)C_ * C_, (long long)C_ * C_);
    conv_bf16<<<CONVGRID((long long)3 * H_ * E_), 256, 0, stream>>>(W_ih0, Wih0_bf, (long long)3 * H_ * E_, (long long)3 * H_ * E_);
    conv_bf16<<<CONVGRID((long long)3 * H_ * H_), 256, 0, stream>>>(W_hh0, Whh0_bf, (long long)3 * H_ * H_, (long long)3 * H_ * H_);
    conv_bf16<<<CONVGRID((long long)3 * H_ * C_), 256, 0, stream>>>(W_ih1, Wih1_bf, (long long)3 * H_ * C_, (long long)3 * H_ * C_);
    conv_bf16<<<CONVGRID((long long)3 * H_ * H_), 256, 0, stream>>>(W_hh1, Whh1_bf, (long long)3 * H_ * H_, (long long)3 * H_ * H_);
    conv_bf16<<<CONVGRID((long long)C_ * H_), 256, 0, stream>>>(W_h2c, Wh2c_bf, (long long)C_ * H_, (long long)C_ * H_);
    conv_bf16<<<CONVGRID((long long)E_ * H_), 256, 0, stream>>>(W_h2o, Wh2o_bf, (long long)E_ * H_, (long long)E_ * H_);
    conv_bf16<<<CONVGRID((long long)V_ * E_), 256, 0, stream>>>(W_o2p, Wo2p_bf, (long long)V_ * E_, (long long)V_ * E_);
    gather_emb_bf<<<MP_, 128, 0, stream>>>(emb, y, xe_bf);
    // ctx_p = ctx @ W_c2c^T -> fp32 (union), then bf16
    mfma_nt<0><<<dim3(C_ / 128, (S_ * B_) / 128), 256, 0, stream>>>(ctx_bf, Wc2c_bf, nullptr,
                                                                    ctx_p, nullptr, nullptr, C_, C_, 0);
    conv_bf16<<<CONVGRID((long long)S_ * B_ * C_), 256, 0, stream>>>(ctx_p, ctxp_bf, (long long)S_ * B_ * C_, (long long)S_ * B_ * C_);
    // gi0_all = x_emb @ W_ih0^T for all steps -> bf16 (overwrites ctx_p region)
    mfma_nt<3><<<dim3(3072 / 128, MP_ / 128), 256, 0, stream>>>(xe_bf, Wih0_bf, nullptr,
                                                                nullptr, gi0_bf, nullptr, 3072, E_, 0);
    // zero h2_bf pad rows (R_..MP_)
    conv_bf16<<<CONVGRID((long long)(MP_ - R_) * H_), 256, 0, stream>>>((const float*)d_ws, h2_bf + (size_t)R_ * H_,
                                                                        0LL, (long long)(MP_ - R_) * H_);
    zero_bar<<<1, 256, 0, stream>>>(barcnt);

    // ---- the whole decode loop in ONE persistent kernel ----
    decode_loop<<<NB_, 256, 0, stream>>>(gi0_bf, Whh0_bf, b_ih0, b_hh0,
                                         Wih1_bf, Whh1_bf, b_ih1, b_hh1,
                                         Wh2c_bf, w_mlp, ctxp_bf, ctx_bf,
                                         P, Ph, h1f, h1bf, zbf, h2f, h2_bf, barcnt);

    // ---- batched tail (bf16 MFMA) ----
    mfma_nt<1><<<dim3(E_ / 128, MP_ / 128), 256, 0, stream>>>(h2_bf, Wh2o_bf, b_h2o,
                                                              logit_all, lg_bf, nullptr, E_, H_, 0);
    mfma_nt<2><<<dim3(V_ / 128, MP_ / 128), 256, 0, stream>>>(lg_bf, Wo2p_bf, b_o2p,
                                                              nullptr, nullptr, pp, V_, E_, NT2);
    row_loss_k<<<R_, 64, 0, stream>>>(pp, logit_all, W_o2p, b_o2p, y, rl);
    sum_k<<<1, 256, 0, stream>>>(rl, out);
}

// Round 4
// 7731.240 us; speedup vs baseline: 5.2855x; 2.1160x over previous
//
#include <hip/hip_runtime.h>
#include <math.h>

#define T_ 100
#define B_ 64
#define S_ 128
#define E_ 512
#define H_ 1024
#define C_ 512
#define V_ 32000
#define TS_ 99            // T-1 steps
#define R_ (TS_ * B_)     // 6336 rows
#define MP_ 6400          // rows padded to multiple of 128 for MFMA
#define NT2 250           // vocab n-tiles of 128
#define NB_ 256           // persistent-kernel grid
#define BH_ (B_ * H_)

typedef unsigned short ushort_t;
typedef __attribute__((ext_vector_type(8))) short short8;
typedef __attribute__((ext_vector_type(4))) float f32x4;
typedef __attribute__((ext_vector_type(4))) unsigned int u32x4;

__device__ __forceinline__ float sigm_(float x) { return 1.0f / (1.0f + __expf(-x)); }
__device__ __forceinline__ float tanh_(float x) { float e = __expf(2.0f * x); return 1.0f - 2.0f / (e + 1.0f); }
__device__ __forceinline__ ushort_t f2bf(float f) {
    unsigned u = __float_as_uint(f);
    unsigned r = (u + 0x7FFF + ((u >> 16) & 1)) >> 16;
    return (ushort_t)r;
}
__device__ __forceinline__ float bf2f(ushort_t u) { return __uint_as_float(((unsigned)u) << 16); }

__device__ __forceinline__ float wred(float v) {
    #pragma unroll
    for (int o = 32; o; o >>= 1) v += __shfl_down(v, o);
    return v;
}
__device__ __forceinline__ float wmax(float v) {
    #pragma unroll
    for (int o = 32; o; o >>= 1) v = fmaxf(v, __shfl_down(v, o));
    return v;
}

// ---- coherent (sc0 sc1) store helpers: fire-and-forget; drained at gbar ----
__device__ __forceinline__ void stf_sc(const float* p, float v) {
    asm volatile("global_store_dword %0, %1, off sc0 sc1" :: "v"(p), "v"(v) : "memory");
}
__device__ __forceinline__ void stu_sc(const void* p, unsigned v) {
    asm volatile("global_store_dword %0, %1, off sc0 sc1" :: "v"(p), "v"(v) : "memory");
}
__device__ __forceinline__ void sts_sc(const void* p, unsigned v) {
    asm volatile("global_store_short %0, %1, off sc0 sc1" :: "v"(p), "v"(v) : "memory");
}

// ---------------------------------------------------------------------------
// Fence-free hierarchical grid barrier. Mutable data travels via sc0/sc1
// accesses (device-coherent point), so visibility needs only vmcnt(0) on the
// producer side — NO buffer_wbl2/buffer_inv (the R3 26us/barrier pathology).
// ---------------------------------------------------------------------------
__device__ __forceinline__ unsigned ld_rlx(unsigned* p) {
    return __hip_atomic_load(p, __ATOMIC_RELAXED, __HIP_MEMORY_SCOPE_AGENT);
}
__device__ __forceinline__ void st_rlx(unsigned* p, unsigned v) {
    __hip_atomic_store(p, v, __ATOMIC_RELAXED, __HIP_MEMORY_SCOPE_AGENT);
}

__device__ __forceinline__ void gbar(unsigned* bar, unsigned ep) {
    asm volatile("s_waitcnt vmcnt(0)" ::: "memory");   // each wave drains its sc stores
    __syncthreads();
    if (threadIdx.x == 0) {
        const int blk = blockIdx.x;
        const int g = blk >> 5;           // 8 groups of 32 blocks
        __hip_atomic_fetch_add(&bar[g * 32], 1u, __ATOMIC_RELAXED, __HIP_MEMORY_SCOPE_AGENT);
        if ((blk & 31) == 0) {
            while (ld_rlx(&bar[g * 32]) < 32u * ep) __builtin_amdgcn_s_sleep(1);
            __hip_atomic_fetch_add(&bar[256], 1u, __ATOMIC_RELAXED, __HIP_MEMORY_SCOPE_AGENT);
            if (blk == 0) {
                while (ld_rlx(&bar[256]) < 8u * ep) __builtin_amdgcn_s_sleep(1);
                st_rlx(&bar[288], ep);
            }
            while (ld_rlx(&bar[288]) < ep) __builtin_amdgcn_s_sleep(1);
            st_rlx(&bar[(10 + g) * 32], ep);
        }
        while (ld_rlx(&bar[(10 + g) * 32]) < ep) __builtin_amdgcn_s_sleep(1);
    }
    __syncthreads();
}

// prefetch full 64x256 bf16 A-slice (8 x dwordx4 per thread), coherent, 1 wait
__device__ __forceinline__ void prefA_sc(const ushort_t* base, int lda,
                                         int row0, int c8, u32x4* a) {
    const ushort_t* p0 = base + (size_t)row0 * lda + c8 * 8;
    const ushort_t* p1 = base + (size_t)(row0 + 32) * lda + c8 * 8;
    asm volatile(
        "global_load_dwordx4 %0, %8, off sc0 sc1\n\t"
        "global_load_dwordx4 %1, %9, off sc0 sc1\n\t"
        "global_load_dwordx4 %2, %10, off sc0 sc1\n\t"
        "global_load_dwordx4 %3, %11, off sc0 sc1\n\t"
        "global_load_dwordx4 %4, %12, off sc0 sc1\n\t"
        "global_load_dwordx4 %5, %13, off sc0 sc1\n\t"
        "global_load_dwordx4 %6, %14, off sc0 sc1\n\t"
        "global_load_dwordx4 %7, %15, off sc0 sc1\n\t"
        "s_waitcnt vmcnt(0)"
        : "=&v"(a[0]), "=&v"(a[1]), "=&v"(a[2]), "=&v"(a[3]),
          "=&v"(a[4]), "=&v"(a[5]), "=&v"(a[6]), "=&v"(a[7])
        : "v"(p0), "v"(p1),
          "v"(p0 + 64), "v"(p1 + 64),
          "v"(p0 + 128), "v"(p1 + 128),
          "v"(p0 + 192), "v"(p1 + 192)
        : "memory");
}

// ---------------------------------------------------------------------------
// 64x64 output tile, K=256 slice, bf16 MFMA. A read coherent (prefetched),
// W read cached (read-only), output stored coherent into slot-interleaved P:
// element (row, col) -> Pbase[(row*NP + col)*SW + slot]
// ---------------------------------------------------------------------------
__device__ __forceinline__ void gemm64(const ushort_t* __restrict__ Ap, int lda,
                                       const ushort_t* __restrict__ Wp,
                                       float* __restrict__ Pbase, int NP, int SW, int slot,
                                       ushort_t* As, ushort_t* Bs) {
    const int tid = threadIdx.x;
    const int w = tid >> 6, lane = tid & 63;
    const int quad = lane >> 4, l16 = lane & 15;
    const int row0 = tid >> 3, c8 = tid & 7;
    u32x4 areg[8];
    prefA_sc(Ap, lda, row0, c8, areg);
    f32x4 acc[4] = {};
    #pragma unroll
    for (int kc4 = 0; kc4 < 4; ++kc4) {
        uint4 vb0 = *(const uint4*)(Wp + (size_t)row0 * lda + kc4 * 64 + c8 * 8);
        uint4 vb1 = *(const uint4*)(Wp + (size_t)(row0 + 32) * lda + kc4 * 64 + c8 * 8);
        __syncthreads();
        *(u32x4*)(&As[row0 * 72 + c8 * 8]) = areg[kc4 * 2];
        *(u32x4*)(&As[(row0 + 32) * 72 + c8 * 8]) = areg[kc4 * 2 + 1];
        *(uint4*)(&Bs[row0 * 72 + c8 * 8]) = vb0;
        *(uint4*)(&Bs[(row0 + 32) * 72 + c8 * 8]) = vb1;
        __syncthreads();
        #pragma unroll
        for (int ks2 = 0; ks2 < 2; ++ks2) {
            short8 bfrag = *(const short8*)(&Bs[(w * 16 + l16) * 72 + ks2 * 32 + quad * 8]);
            #pragma unroll
            for (int i = 0; i < 4; ++i) {
                short8 afrag = *(const short8*)(&As[(i * 16 + l16) * 72 + ks2 * 32 + quad * 8]);
                acc[i] = __builtin_amdgcn_mfma_f32_16x16x32_bf16(afrag, bfrag, acc[i], 0, 0, 0);
            }
        }
    }
    const int col = w * 16 + l16;
    #pragma unroll
    for (int i = 0; i < 4; ++i)
        #pragma unroll
        for (int r = 0; r < 4; ++r)
            stf_sc(Pbase + ((size_t)(i * 16 + quad * 4 + r) * NP + col) * SW + slot, acc[i][r]);
}

// ---------------------------------------------------------------------------
// Persistent decode loop. P layout: [b][3072][8] slots (0..3 h-part, 4..5
// x-part of GRU1). Ph layout: [b][512][4]. All mutable traffic sc0/sc1.
// ---------------------------------------------------------------------------
__global__ __launch_bounds__(256) void decode_loop(
    const ushort_t* __restrict__ gi0_bf,
    const ushort_t* __restrict__ Whh0,
    const float* __restrict__ bi0, const float* __restrict__ bh0,
    const ushort_t* __restrict__ Wih1, const ushort_t* __restrict__ Whh1,
    const float* __restrict__ bi1, const float* __restrict__ bh1,
    const ushort_t* __restrict__ Wh2c, const float* __restrict__ wmlp,
    const ushort_t* __restrict__ ctxp_bf, const ushort_t* __restrict__ ctx_bf,
    float* __restrict__ P, float* __restrict__ Ph,
    float* __restrict__ h1f, ushort_t* __restrict__ h1bf, ushort_t* __restrict__ zbf,
    float* __restrict__ h2f, ushort_t* __restrict__ h2bf,
    unsigned* __restrict__ bar) {
    __shared__ __align__(16) ushort_t As[64 * 72];
    __shared__ __align__(16) ushort_t Bs[64 * 72];
    const int blk = blockIdx.x;
    const int tid = threadIdx.x;
    unsigned ep = 0;
    for (int t = 0; t < TS_; ++t) {
        const int cur = t & 1, prv = cur ^ 1;
        // ---- P1: gh0 = h2(t-1) @ Whh0^T -> P slots 0..3 (skip at t=0)
        if (t && blk < 192) {
            int ct = blk % 48, ks = blk / 48;
            gemm64(h2bf + (size_t)(t - 1) * BH_ + ks * 256, H_,
                   Whh0 + (size_t)(ct * 64) * H_ + ks * 256,
                   P + (size_t)ct * 64 * 8, 3072, 8, ks, As, Bs);
        }
        gbar(bar, ++ep);
        // ---- P2: gate0 -> h1
        {
            int p = blk * 256 + tid;
            int b = p >> 10, j = p & 1023;
            const ushort_t* g = gi0_bf + (size_t)(t * B_ + b) * 3072;
            float ir = bi0[j] + bf2f(g[j]);
            float iz = bi0[1024 + j] + bf2f(g[1024 + j]);
            float in_ = bi0[2048 + j] + bf2f(g[2048 + j]);
            float hr = bh0[j], hz = bh0[1024 + j], hn = bh0[2048 + j];
            float hprev = 0.0f;
            if (t) {
                const float* pr = P + ((size_t)b * 3072 + j) * 8;
                const float* pz = P + ((size_t)b * 3072 + 1024 + j) * 8;
                const float* pn = P + ((size_t)b * 3072 + 2048 + j) * 8;
                const float* ph2 = h2f + (size_t)prv * BH_ + b * 1024 + j;
                f32x4 qr, qz, qn; float hp2;
                asm volatile(
                    "global_load_dwordx4 %0, %4, off sc0 sc1\n\t"
                    "global_load_dwordx4 %1, %5, off sc0 sc1\n\t"
                    "global_load_dwordx4 %2, %6, off sc0 sc1\n\t"
                    "global_load_dword %3, %7, off sc0 sc1\n\t"
                    "s_waitcnt vmcnt(0)"
                    : "=&v"(qr), "=&v"(qz), "=&v"(qn), "=&v"(hp2)
                    : "v"(pr), "v"(pz), "v"(pn), "v"(ph2) : "memory");
                hr += qr[0] + qr[1] + qr[2] + qr[3];
                hz += qz[0] + qz[1] + qz[2] + qz[3];
                hn += qn[0] + qn[1] + qn[2] + qn[3];
                hprev = hp2;
            }
            float r = sigm_(ir + hr), z = sigm_(iz + hz);
            float n = tanh_(in_ + r * hn);
            float h = (1.0f - z) * n + z * hprev;
            stf_sc(h1f + b * 1024 + j, h);
            sts_sc(h1bf + b * 1024 + j, (unsigned)f2bf(h));
        }
        gbar(bar, ++ep);
        // ---- P3: gh1 = h1 @ Whh1^T -> P slots 0..3; hid = h1 @ Wh2c^T -> Ph
        if (blk < 192) {
            int ct = blk % 48, ks = blk / 48;
            gemm64(h1bf + ks * 256, H_, Whh1 + (size_t)(ct * 64) * H_ + ks * 256,
                   P + (size_t)ct * 64 * 8, 3072, 8, ks, As, Bs);
        } else if (blk < 224) {
            int q = blk - 192;
            int ct = q % 8, ks = q / 8;
            gemm64(h1bf + ks * 256, H_, Wh2c + (size_t)(ct * 64) * H_ + ks * 256,
                   Ph + (size_t)ct * 64 * 4, 512, 4, ks, As, Bs);
        }
        gbar(bar, ++ep);
        // ---- P4: attention -> zbf   (one block per batch row)
        if (blk < 64) {
            float* hd = (float*)As;                 // 512 f32
            float* wm = (float*)(As + 2048);        // 512 f32
            float* sc = (float*)Bs;                 // 128 f32
            const int b = blk;
            {
                const float* pk0 = Ph + ((size_t)b * 512 + tid) * 4;
                const float* pk1 = Ph + ((size_t)b * 512 + tid + 256) * 4;
                f32x4 qa, qb;
                asm volatile(
                    "global_load_dwordx4 %0, %2, off sc0 sc1\n\t"
                    "global_load_dwordx4 %1, %3, off sc0 sc1\n\t"
                    "s_waitcnt vmcnt(0)"
                    : "=&v"(qa), "=&v"(qb) : "v"(pk0), "v"(pk1) : "memory");
                hd[tid] = qa[0] + qa[1] + qa[2] + qa[3];
                hd[tid + 256] = qb[0] + qb[1] + qb[2] + qb[3];
                wm[tid] = wmlp[tid];
                wm[tid + 256] = wmlp[tid + 256];
            }
            __syncthreads();
            const int wave = tid >> 6, lane = tid & 63;
            for (int s = wave; s < 128; s += 4) {
                const ushort_t* cp = ctxp_bf + ((size_t)s * B_ + b) * 512 + lane * 8;
                short8 v = *(const short8*)cp;
                float acc = 0;
                #pragma unroll
                for (int k = 0; k < 8; ++k) {
                    int c = lane * 8 + k;
                    acc += tanh_(bf2f((ushort_t)v[k]) + hd[c]) * wm[c];
                }
                acc = wred(acc);
                if (lane == 0) sc[s] = acc;
            }
            __syncthreads();
            if (wave == 0) {
                float s0 = sc[lane], s1 = sc[lane + 64];
                float m = fmaxf(s0, s1);
                m = wmax(m); m = __shfl(m, 0);
                float e0 = __expf(s0 - m), e1 = __expf(s1 - m);
                float ssum = wred(e0 + e1); ssum = __shfl(ssum, 0);
                float inv = 1.0f / ssum;
                sc[lane] = e0 * inv; sc[lane + 64] = e1 * inv;
            }
            __syncthreads();
            {
                const int c = tid * 2;
                float a0 = 0, a1 = 0;
                #pragma unroll 8
                for (int s = 0; s < 128; ++s) {
                    ushort2 u = *(const ushort2*)(ctx_bf + ((size_t)s * B_ + b) * 512 + c);
                    float w_ = sc[s];
                    a0 = fmaf(w_, bf2f(u.x), a0);
                    a1 = fmaf(w_, bf2f(u.y), a1);
                }
                unsigned pk = (unsigned)f2bf(a0) | ((unsigned)f2bf(a1) << 16);
                stu_sc(zbf + (size_t)b * 512 + c, pk);
            }
        }
        gbar(bar, ++ep);
        // ---- P5: gi1 = z @ Wih1^T -> P slots 4..5
        if (blk < 96) {
            int ct = blk % 48, ks = blk / 48;   // ks in {0,1}
            gemm64(zbf + ks * 256, C_, Wih1 + (size_t)(ct * 64) * C_ + ks * 256,
                   P + (size_t)ct * 64 * 8, 3072, 8, 4 + ks, As, Bs);
        }
        gbar(bar, ++ep);
        // ---- P6: gate1 -> h2 (fp32 ping-pong + bf16 history)
        {
            int p = blk * 256 + tid;
            int b = p >> 10, j = p & 1023;
            float ir = bi1[j], iz = bi1[1024 + j], in_ = bi1[2048 + j];
            float hr = bh1[j], hz = bh1[1024 + j], hn = bh1[2048 + j];
            const float* pr = P + ((size_t)b * 3072 + j) * 8;
            const float* pz = P + ((size_t)b * 3072 + 1024 + j) * 8;
            const float* pn = P + ((size_t)b * 3072 + 2048 + j) * 8;
            const float* ph1 = h1f + b * 1024 + j;
            f32x4 qr, qri, qz, qzi, qn, qni; float hp1;
            asm volatile(
                "global_load_dwordx4 %0, %7, off sc0 sc1\n\t"
                "global_load_dwordx4 %1, %7, off offset:16 sc0 sc1\n\t"
                "global_load_dwordx4 %2, %8, off sc0 sc1\n\t"
                "global_load_dwordx4 %3, %8, off offset:16 sc0 sc1\n\t"
                "global_load_dwordx4 %4, %9, off sc0 sc1\n\t"
                "global_load_dwordx4 %5, %9, off offset:16 sc0 sc1\n\t"
                "global_load_dword %6, %10, off sc0 sc1\n\t"
                "s_waitcnt vmcnt(0)"
                : "=&v"(qr), "=&v"(qri), "=&v"(qz), "=&v"(qzi), "=&v"(qn), "=&v"(qni), "=&v"(hp1)
                : "v"(pr), "v"(pz), "v"(pn), "v"(ph1) : "memory");
            hr += qr[0] + qr[1] + qr[2] + qr[3];  ir += qri[0] + qri[1];
            hz += qz[0] + qz[1] + qz[2] + qz[3];  iz += qzi[0] + qzi[1];
            hn += qn[0] + qn[1] + qn[2] + qn[3];  in_ += qni[0] + qni[1];
            float r = sigm_(ir + hr), z = sigm_(iz + hz);
            float n = tanh_(in_ + r * hn);
            float h = (1.0f - z) * n + z * hp1;
            stf_sc(h2f + (size_t)cur * BH_ + b * 1024 + j, h);
            sts_sc(h2bf + (size_t)t * BH_ + b * 1024 + j, (unsigned)f2bf(h));
        }
        gbar(bar, ++ep);
    }
}

// ---------------------------------------------------------------------------
// bf16 MFMA GEMM-NT, 128x128 tile. EPI==0: fp32 store (+opt bias).
// EPI==1: tanh(acc+bias) -> fp32 + bf16. EPI==2: fused LSE partials.
// EPI==3: bf16-only store (no bias).
// ---------------------------------------------------------------------------
template <int EPI>
__global__ __launch_bounds__(256) void mfma_nt(const ushort_t* __restrict__ A,
                                               const ushort_t* __restrict__ Bw,
                                               const float* __restrict__ bias,
                                               float* __restrict__ Cf,
                                               ushort_t* __restrict__ Cbf,
                                               float2* __restrict__ pp,
                                               int N, int K, int NT) {
    __shared__ ushort_t As[128 * 72];
    __shared__ ushort_t Bs[128 * 72];
    __shared__ float smM[2][128], smS[2][128];
    const int tid = threadIdx.x;
    const int m0 = blockIdx.y * 128, n0 = blockIdx.x * 128;
    const int w = tid >> 6, lane = tid & 63;
    const int quad = lane >> 4, l16 = lane & 15;
    f32x4 acc[4][4] = {};
    for (int kc = 0; kc < K; kc += 64) {
        __syncthreads();
        #pragma unroll
        for (int i = 0; i < 4; ++i) {
            int cid = i * 256 + tid;
            int row = cid >> 3, c8 = cid & 7;
            uint4 va = *(const uint4*)(A + (size_t)(m0 + row) * K + kc + c8 * 8);
            *(uint4*)(&As[row * 72 + c8 * 8]) = va;
            uint4 vb = *(const uint4*)(Bw + (size_t)(n0 + row) * K + kc + c8 * 8);
            *(uint4*)(&Bs[row * 72 + c8 * 8]) = vb;
        }
        __syncthreads();
        #pragma unroll
        for (int ks = 0; ks < 2; ++ks) {
            short8 af[4], bfr[4];
            #pragma unroll
            for (int i = 0; i < 4; ++i)
                af[i] = *(const short8*)(&As[((w >> 1) * 64 + i * 16 + l16) * 72 + ks * 32 + quad * 8]);
            #pragma unroll
            for (int j = 0; j < 4; ++j)
                bfr[j] = *(const short8*)(&Bs[((w & 1) * 64 + j * 16 + l16) * 72 + ks * 32 + quad * 8]);
            #pragma unroll
            for (int i = 0; i < 4; ++i)
                #pragma unroll
                for (int j = 0; j < 4; ++j)
                    acc[i][j] = __builtin_amdgcn_mfma_f32_16x16x32_bf16(af[i], bfr[j], acc[i][j], 0, 0, 0);
        }
    }
    const int colbase = n0 + (w & 1) * 64;
    const int rowbase = m0 + (w >> 1) * 64;
    if (EPI == 0) {
        #pragma unroll
        for (int j = 0; j < 4; ++j) {
            int col = colbase + j * 16 + l16;
            float bv = bias ? bias[col] : 0.0f;
            #pragma unroll
            for (int i = 0; i < 4; ++i)
                #pragma unroll
                for (int r = 0; r < 4; ++r) {
                    int row = rowbase + i * 16 + quad * 4 + r;
                    Cf[(size_t)row * N + col] = acc[i][j][r] + bv;
                }
        }
    } else if (EPI == 1) {
        #pragma unroll
        for (int j = 0; j < 4; ++j) {
            int col = colbase + j * 16 + l16;
            float bv = bias[col];
            #pragma unroll
            for (int i = 0; i < 4; ++i)
                #pragma unroll
                for (int r = 0; r < 4; ++r) {
                    int row = rowbase + i * 16 + quad * 4 + r;
                    float v = tanh_(acc[i][j][r] + bv);
                    Cf[(size_t)row * N + col] = v;
                    Cbf[(size_t)row * N + col] = f2bf(v);
                }
        }
    } else if (EPI == 3) {
        #pragma unroll
        for (int j = 0; j < 4; ++j) {
            int col = colbase + j * 16 + l16;
            #pragma unroll
            for (int i = 0; i < 4; ++i)
                #pragma unroll
                for (int r = 0; r < 4; ++r) {
                    int row = rowbase + i * 16 + quad * 4 + r;
                    Cbf[(size_t)row * N + col] = f2bf(acc[i][j][r]);
                }
        }
    } else {  // EPI == 2: LSE partials
        float bv[4];
        #pragma unroll
        for (int j = 0; j < 4; ++j) bv[j] = bias[colbase + j * 16 + l16];
        #pragma unroll
        for (int i = 0; i < 4; ++i) {
            #pragma unroll
            for (int r = 0; r < 4; ++r) {
                float x0 = acc[i][0][r] + bv[0], x1 = acc[i][1][r] + bv[1];
                float x2 = acc[i][2][r] + bv[2], x3 = acc[i][3][r] + bv[3];
                float mx = fmaxf(fmaxf(x0, x1), fmaxf(x2, x3));
                #pragma unroll
                for (int o = 1; o < 16; o <<= 1) mx = fmaxf(mx, __shfl_xor(mx, o));
                float s = __expf(x0 - mx) + __expf(x1 - mx) + __expf(x2 - mx) + __expf(x3 - mx);
                #pragma unroll
                for (int o = 1; o < 16; o <<= 1) s += __shfl_xor(s, o);
                if (l16 == 0) {
                    int rr = (w >> 1) * 64 + i * 16 + quad * 4 + r;
                    smM[w & 1][rr] = mx;
                    smS[w & 1][rr] = s;
                }
            }
        }
        __syncthreads();
        if (tid < 128) {
            float ma = smM[0][tid], mb = smM[1][tid];
            float M = fmaxf(ma, mb);
            float S = smS[0][tid] * __expf(ma - M) + smS[1][tid] * __expf(mb - M);
            pp[(size_t)(m0 + tid) * NT + blockIdx.x] = make_float2(M, S);
        }
    }
}

// fp32 -> bf16 convert with zero-pad beyond n_valid. block 256, 4 elems/thread.
__global__ __launch_bounds__(256) void conv_bf16(const float* __restrict__ src,
                                                 ushort_t* __restrict__ dst,
                                                 long long n_valid, long long n_total) {
    long long base = ((long long)blockIdx.x * 256 + threadIdx.x) * 4;
    if (base >= n_total) return;
    ushort_t o[4] = {0, 0, 0, 0};
    if (base < n_valid) {
        float4 v = *(const float4*)(src + base);
        o[0] = f2bf(v.x); o[1] = f2bf(v.y); o[2] = f2bf(v.z); o[3] = f2bf(v.w);
    }
    *(ushort2*)(dst + base) = make_ushort2(o[0], o[1]);
    *(ushort2*)(dst + base + 2) = make_ushort2(o[2], o[3]);
}

// gather embedding rows to bf16 with zero pad rows r >= R_.
__global__ __launch_bounds__(128) void gather_emb_bf(const float* __restrict__ emb,
                                                     const int* __restrict__ y,
                                                     ushort_t* __restrict__ xbf) {
    const int r = blockIdx.x;
    ushort_t* dst = xbf + (size_t)r * 512 + threadIdx.x * 4;
    if (r >= R_) {
        *(ushort2*)(dst) = make_ushort2(0, 0);
        *(ushort2*)(dst + 2) = make_ushort2(0, 0);
        return;
    }
    const int tok = y[r];
    const float* src = emb + (size_t)tok * 512;
    float4 v = *(const float4*)(src + threadIdx.x * 4);
    *(ushort2*)(dst) = make_ushort2(f2bf(v.x), f2bf(v.y));
    *(ushort2*)(dst + 2) = make_ushort2(f2bf(v.z), f2bf(v.w));
}

__global__ __launch_bounds__(256) void zero_bar(unsigned* p) {
    for (int i = threadIdx.x; i < 1024; i += 256) p[i] = 0u;
}

// combine LSE partials + target logit -> per-row loss. grid = R_, block 64.
__global__ __launch_bounds__(64) void row_loss_k(const float2* __restrict__ pp,
                                                 const float* __restrict__ logit_all,
                                                 const float* __restrict__ Wv,
                                                 const float* __restrict__ bv,
                                                 const int* __restrict__ y,
                                                 float* __restrict__ rl) {
    const int r = blockIdx.x;
    const int lane = threadIdx.x;
    const int t = r / B_, b = r % B_;
    const int tgt = y[(t + 1) * B_ + b];
    float m = -1e30f;
    for (int i = lane; i < NT2; i += 64) m = fmaxf(m, pp[(size_t)r * NT2 + i].x);
    m = wmax(m); m = __shfl(m, 0);
    float s = 0;
    for (int i = lane; i < NT2; i += 64) {
        float2 p = pp[(size_t)r * NT2 + i];
        s += p.y * __expf(p.x - m);
    }
    s = wred(s);
    float d = 0;
    for (int k = lane; k < E_; k += 64) d += logit_all[(size_t)r * E_ + k] * Wv[(size_t)tgt * E_ + k];
    d = wred(d);
    if (lane == 0) {
        float lse = m + logf(s);
        rl[r] = (tgt != 0) ? (lse - (d + bv[tgt])) : 0.0f;
    }
}

__global__ __launch_bounds__(256) void sum_k(const float* __restrict__ rl, float* __restrict__ out) {
    float s = 0;
    for (int i = threadIdx.x; i < R_; i += 256) s += rl[i];
    __shared__ float red[4];
    s = wred(s);
    if ((threadIdx.x & 63) == 0) red[threadIdx.x >> 6] = s;
    __syncthreads();
    if (threadIdx.x == 0) out[0] = red[0] + red[1] + red[2] + red[3];
}

extern "C" void kernel_launch(void* const* d_in, const int* in_sizes, int n_in,
                              void* d_out, int out_size, void* d_ws, size_t ws_size,
                              hipStream_t stream) {
    const int*   y     = (const int*)d_in[0];
    const float* ctx   = (const float*)d_in[1];
    const float* emb   = (const float*)d_in[2];
    const float* W_ih0 = (const float*)d_in[3];
    const float* W_hh0 = (const float*)d_in[4];
    const float* b_ih0 = (const float*)d_in[5];
    const float* b_hh0 = (const float*)d_in[6];
    const float* W_ih1 = (const float*)d_in[7];
    const float* W_hh1 = (const float*)d_in[8];
    const float* b_ih1 = (const float*)d_in[9];
    const float* b_hh1 = (const float*)d_in[10];
    const float* W_c2c = (const float*)d_in[11];
    const float* W_h2c = (const float*)d_in[12];
    const float* w_mlp = (const float*)d_in[13];
    const float* W_h2o = (const float*)d_in[14];
    const float* b_h2o = (const float*)d_in[15];
    const float* W_o2p = (const float*)d_in[16];
    const float* b_o2p = (const float*)d_in[17];
    float* out = (float*)d_out;

    float* ws = (float*)d_ws;
    ushort_t* ctxp_bf = (ushort_t*)ws; ws += (size_t)S_ * B_ * C_ / 2;   // 8.4 MB
    ushort_t* ctx_bf  = (ushort_t*)ws; ws += (size_t)S_ * B_ * C_ / 2;   // 8.4 MB
    ushort_t* xe_bf   = (ushort_t*)ws; ws += (size_t)MP_ * E_ / 2;       // 6.6 MB (zero-padded)
    float* P          = ws; ws += (size_t)B_ * 3072 * 8;                 // 6.3 MB  [b][j][8]
    float* Ph         = ws; ws += (size_t)B_ * 512 * 4;                  // 0.5 MB  [b][k][4]
    float* h1f        = ws; ws += (size_t)B_ * H_;
    ushort_t* h1bf    = (ushort_t*)ws; ws += (size_t)B_ * H_ / 2;
    ushort_t* zbf     = (ushort_t*)ws; ws += (size_t)B_ * C_ / 2;
    float* h2f        = ws; ws += (size_t)2 * B_ * H_;                   // ping-pong fp32
    ushort_t* h2_bf   = (ushort_t*)ws; ws += (size_t)MP_ * H_ / 2;       // 13.1 MB history
    ushort_t* Wih0_bf = (ushort_t*)ws; ws += (size_t)3 * H_ * E_ / 2;
    ushort_t* Whh0_bf = (ushort_t*)ws; ws += (size_t)3 * H_ * H_ / 2;
    ushort_t* Wih1_bf = (ushort_t*)ws; ws += (size_t)3 * H_ * C_ / 2;
    ushort_t* Whh1_bf = (ushort_t*)ws; ws += (size_t)3 * H_ * H_ / 2;
    ushort_t* Wh2c_bf = (ushort_t*)ws; ws += (size_t)C_ * H_ / 2;
    ushort_t* Wc2c_bf = (ushort_t*)ws; ws += (size_t)C_ * C_ / 2;
    ushort_t* Wh2o_bf = (ushort_t*)ws; ws += (size_t)E_ * H_ / 2;
    ushort_t* Wo2p_bf = (ushort_t*)ws; ws += (size_t)V_ * E_ / 2;        // 32.8 MB
    unsigned* barcnt  = (unsigned*)ws; ws += 1024;
    // union region: precompute ctx_p | loop gi0_bf | tail logit/lg/pp/rl
    float* uni        = ws; ws += (size_t)MP_ * 3072 / 2;                // 39.3 MB
    float* ctx_p      = uni;                                             // S*B*C fp32 (precompute)
    ushort_t* gi0_bf  = (ushort_t*)uni;                                  // MP_*3072 bf16 (loop)
    float* logit_all  = uni;                                             // MP_*E fp32 (tail)
    ushort_t* lg_bf   = (ushort_t*)(uni + (size_t)MP_ * E_);             // MP_*E bf16 (tail)
    float2* pp        = (float2*)(uni + (size_t)MP_ * E_ + (size_t)MP_ * E_ / 2);
    float* rl         = uni + (size_t)MP_ * E_ + (size_t)MP_ * E_ / 2 + (size_t)MP_ * NT2 * 2;

    #define CONVGRID(n) dim3((unsigned)(((n) / 4 + 255) / 256))

    // ---- batched precompute ----
    conv_bf16<<<CONVGRID((long long)S_ * B_ * C_), 256, 0, stream>>>(ctx, ctx_bf, (long long)S_ * B_ * C_, (long long)S_ * B_ * C_);
    conv_bf16<<<CONVGRID((long long)C_ * C_), 256, 0, stream>>>(W_c2c, Wc2c_bf, (long long)C_ * C_, (long long)C_ * C_);
    conv_bf16<<<CONVGRID((long long)3 * H_ * E_), 256, 0, stream>>>(W_ih0, Wih0_bf, (long long)3 * H_ * E_, (long long)3 * H_ * E_);
    conv_bf16<<<CONVGRID((long long)3 * H_ * H_), 256, 0, stream>>>(W_hh0, Whh0_bf, (long long)3 * H_ * H_, (long long)3 * H_ * H_);
    conv_bf16<<<CONVGRID((long long)3 * H_ * C_), 256, 0, stream>>>(W_ih1, Wih1_bf, (long long)3 * H_ * C_, (long long)3 * H_ * C_);
    conv_bf16<<<CONVGRID((long long)3 * H_ * H_), 256, 0, stream>>>(W_hh1, Whh1_bf, (long long)3 * H_ * H_, (long long)3 * H_ * H_);
    conv_bf16<<<CONVGRID((long long)C_ * H_), 256, 0, stream>>>(W_h2c, Wh2c_bf, (long long)C_ * H_, (long long)C_ * H_);
    conv_bf16<<<CONVGRID((long long)E_ * H_), 256, 0, stream>>>(W_h2o, Wh2o_bf, (long long)E_ * H_, (long long)E_ * H_);
    conv_bf16<<<CONVGRID((long long)V_ * E_), 256, 0, stream>>>(W_o2p, Wo2p_bf, (long long)V_ * E_, (long long)V_ * E_);
    gather_emb_bf<<<MP_, 128, 0, stream>>>(emb, y, xe_bf);
    // ctx_p = ctx @ W_c2c^T -> fp32 (union), then bf16
    mfma_nt<0><<<dim3(C_ / 128, (S_ * B_) / 128), 256, 0, stream>>>(ctx_bf, Wc2c_bf, nullptr,
                                                                    ctx_p, nullptr, nullptr, C_, C_, 0);
    conv_bf16<<<CONVGRID((long long)S_ * B_ * C_), 256, 0, stream>>>(ctx_p, ctxp_bf, (long long)S_ * B_ * C_, (long long)S_ * B_ * C_);
    // gi0_all = x_emb @ W_ih0^T for all steps -> bf16 (overwrites ctx_p region)
    mfma_nt<3><<<dim3(3072 / 128, MP_ / 128), 256, 0, stream>>>(xe_bf, Wih0_bf, nullptr,
                                                                nullptr, gi0_bf, nullptr, 3072, E_, 0);
    // zero h2_bf pad rows (R_..MP_)
    conv_bf16<<<CONVGRID((long long)(MP_ - R_) * H_), 256, 0, stream>>>((const float*)d_ws, h2_bf + (size_t)R_ * H_,
                                                                        0LL, (long long)(MP_ - R_) * H_);
    zero_bar<<<1, 256, 0, stream>>>(barcnt);

    // ---- the whole decode loop in ONE persistent kernel ----
    decode_loop<<<NB_, 256, 0, stream>>>(gi0_bf, Whh0_bf, b_ih0, b_hh0,
                                         Wih1_bf, Whh1_bf, b_ih1, b_hh1,
                                         Wh2c_bf, w_mlp, ctxp_bf, ctx_bf,
                                         P, Ph, h1f, h1bf, zbf, h2f, h2_bf, barcnt);

    // ---- batched tail (bf16 MFMA) ----
    mfma_nt<1><<<dim3(E_ / 128, MP_ / 128), 256, 0, stream>>>(h2_bf, Wh2o_bf, b_h2o,
                                                              logit_all, lg_bf, nullptr, E_, H_, 0);
    mfma_nt<2><<<dim3(V_ / 128, MP_ / 128), 256, 0, stream>>>(lg_bf, Wo2p_bf, b_o2p,
                                                              nullptr, nullptr, pp, V_, E_, NT2);
    row_loss_k<<<R_, 64, 0, stream>>>(pp, logit_all, W_o2p, b_o2p, y, rl);
    sum_k<<<1, 256, 0, stream>>>(rl, out);
}